// Round 1
// baseline (846.850 us; speedup 1.0000x reference)
//
#include <hip/hip_runtime.h>

#define NROWS 65536          // B*T
#define DD 512
#define EPS_LN 1e-5f

typedef __bf16 bfx8 __attribute__((ext_vector_type(8)));
typedef float fx4 __attribute__((ext_vector_type(4)));

__device__ __forceinline__ unsigned short f2bf(float f) {
  unsigned int u = __builtin_bit_cast(unsigned int, f);
  u += 0x7fffu + ((u >> 16) & 1u);          // RNE
  return (unsigned short)(u >> 16);
}
__device__ __forceinline__ float bflo(unsigned int u) { return __builtin_bit_cast(float, u << 16); }
__device__ __forceinline__ float bfhi(unsigned int u) { return __builtin_bit_cast(float, u & 0xffff0000u); }
__device__ __forceinline__ unsigned int pack2(float a, float b) {
  return (unsigned int)f2bf(a) | ((unsigned int)f2bf(b) << 16);
}
__device__ __forceinline__ float wave_sum(float v) {
  #pragma unroll
  for (int off = 32; off; off >>= 1) v += __shfl_xor(v, off);
  return v;
}

// ---------------- K0: weight prep ----------------
// WqkvT[j][k] (j<512:Q, <1024:K, else:V) = W[k][j] as bf16.  W1T = ff1_w (already [out][in]) as bf16.
__global__ __launch_bounds__(256) void prep_weights(
    const float* __restrict__ Qw, const float* __restrict__ Kw, const float* __restrict__ Vw,
    const float* __restrict__ ff1w, unsigned short* __restrict__ WqkvT, unsigned short* __restrict__ W1T) {
  int idx = blockIdx.x * 256 + threadIdx.x;
  if (idx < 1536 * 512) {
    int j = idx >> 9, k = idx & 511;
    const float* src = (j < 512) ? Qw : (j < 1024 ? Kw : Vw);
    WqkvT[idx] = f2bf(src[k * 512 + (j & 511)]);
  } else {
    int i2 = idx - 1536 * 512;           // < 512*512 by grid sizing
    W1T[i2] = f2bf(ff1w[i2]);
  }
}

// ---------------- K1: x + pos + pcc + pblr -> LN -> bf16 ----------------
__global__ __launch_bounds__(256) void ln1_kernel(
    const float* __restrict__ x, const float* __restrict__ pcc, const float* __restrict__ pblr,
    const float* __restrict__ pos, const float* __restrict__ lnw, const float* __restrict__ lnb,
    unsigned short* __restrict__ t_in) {
  int row = blockIdx.x * 4 + (threadIdx.x >> 6);
  int lane = threadIdx.x & 63;
  size_t base = (size_t)row * DD + lane * 8;
  int t = row & 15;
  const fx4* x4 = (const fx4*)(x + base);
  const fx4* p4 = (const fx4*)(pcc + base);
  const fx4* q4 = (const fx4*)(pblr + base);
  const fx4* e4 = (const fx4*)(pos + t * DD + lane * 8);
  fx4 a0 = x4[0], a1 = x4[1], b0 = p4[0], b1 = p4[1], c0 = q4[0], c1 = q4[1], d0 = e4[0], d1 = e4[1];
  float s[8];
  #pragma unroll
  for (int j = 0; j < 4; ++j) { s[j] = a0[j] + b0[j] + c0[j] + d0[j]; s[j+4] = a1[j] + b1[j] + c1[j] + d1[j]; }
  float sum = 0.f;
  #pragma unroll
  for (int j = 0; j < 8; ++j) sum += s[j];
  sum = wave_sum(sum);
  float mu = sum * (1.0f / 512.0f);
  float vs = 0.f;
  #pragma unroll
  for (int j = 0; j < 8; ++j) { float d = s[j] - mu; vs += d * d; }
  vs = wave_sum(vs);
  float rs = rsqrtf(vs * (1.0f / 512.0f) + EPS_LN);
  const fx4* w4 = (const fx4*)(lnw + lane * 8);
  const fx4* bb4 = (const fx4*)(lnb + lane * 8);
  fx4 w0 = w4[0], w1 = w4[1], g0 = bb4[0], g1 = bb4[1];
  float o[8];
  #pragma unroll
  for (int j = 0; j < 4; ++j) { o[j] = (s[j] - mu) * rs * w0[j] + g0[j]; o[j+4] = (s[j+4] - mu) * rs * w1[j] + g1[j]; }
  uint4 pk;
  pk.x = pack2(o[0], o[1]); pk.y = pack2(o[2], o[3]); pk.z = pack2(o[4], o[5]); pk.w = pack2(o[6], o[7]);
  *(uint4*)(t_in + base) = pk;
}

// ---------------- K2/K5: GEMM  C[M][ldc] = A[M][512] * BT[N][512]^T ----------------
// 128x128 tile, BK=64, 256 threads = 4 waves (2x2), each wave 64x64 (4x4 frags of 16x16).
__global__ __launch_bounds__(256) void gemm_bt(
    const unsigned short* __restrict__ A, const unsigned short* __restrict__ BT,
    unsigned short* __restrict__ C, int ldc,
    const float* __restrict__ bias, const float* __restrict__ prelu_a) {
  __shared__ unsigned short As[128 * 72];
  __shared__ unsigned short Bs[128 * 72];
  int tid = threadIdx.x;
  int row0 = blockIdx.x * 128, col0 = blockIdx.y * 128;
  int wid = tid >> 6, lane = tid & 63;
  int wm = (wid >> 1) * 64, wn = (wid & 1) * 64;
  fx4 acc[4][4] = {};
  for (int k0 = 0; k0 < 512; k0 += 64) {
    #pragma unroll
    for (int c = 0; c < 4; ++c) {
      int v = c * 256 + tid;
      int r = v >> 3, kk = (v & 7) * 8;
      uint4 da = *(const uint4*)(A + (size_t)(row0 + r) * 512 + k0 + kk);
      uint4 db = *(const uint4*)(BT + (size_t)(col0 + r) * 512 + k0 + kk);
      *(uint4*)(As + r * 72 + kk) = da;
      *(uint4*)(Bs + r * 72 + kk) = db;
    }
    __syncthreads();
    #pragma unroll
    for (int ks = 0; ks < 2; ++ks) {
      int koff = ks * 32 + (lane >> 4) * 8;
      bfx8 af[4], bf[4];
      #pragma unroll
      for (int m = 0; m < 4; ++m) af[m] = *(const bfx8*)(As + (wm + m * 16 + (lane & 15)) * 72 + koff);
      #pragma unroll
      for (int n = 0; n < 4; ++n) bf[n] = *(const bfx8*)(Bs + (wn + n * 16 + (lane & 15)) * 72 + koff);
      #pragma unroll
      for (int m = 0; m < 4; ++m)
        #pragma unroll
        for (int n = 0; n < 4; ++n)
          acc[m][n] = __builtin_amdgcn_mfma_f32_16x16x32_bf16(af[m], bf[n], acc[m][n], 0, 0, 0);
    }
    __syncthreads();
  }
  bool do_prelu = (prelu_a != nullptr);
  float pa = do_prelu ? *prelu_a : 0.f;
  #pragma unroll
  for (int m = 0; m < 4; ++m) {
    #pragma unroll
    for (int n = 0; n < 4; ++n) {
      int rbase = row0 + wm + m * 16 + ((lane >> 4) * 4);
      int cidx = col0 + wn + n * 16 + (lane & 15);
      float bv = bias ? bias[cidx] : 0.f;
      #pragma unroll
      for (int r = 0; r < 4; ++r) {
        float v = acc[m][n][r] + bv;
        if (do_prelu) v = fmaxf(v, 0.f) + pa * fminf(v, 0.f);
        C[(size_t)(rbase + r) * ldc + cidx] = f2bf(v);
      }
    }
  }
}

// ---------------- K3: attention per batch element ----------------
__global__ __launch_bounds__(256) void attn_kernel(
    const unsigned short* __restrict__ qkv, unsigned short* __restrict__ attn_out) {
  __shared__ unsigned short q_s[16 * 520];
  __shared__ unsigned short k_s[16 * 520];
  __shared__ unsigned short v_s[16 * 520];
  __shared__ float p_s[8 * 16 * 18];
  int b = blockIdx.x, tid = threadIdx.x;
  #pragma unroll
  for (int c = 0; c < 12; ++c) {
    int v = c * 256 + tid;        // 0..3071 vec8 ids
    int i = v / 192, colv = v % 192, col = colv * 8;
    uint4 d = *(const uint4*)(qkv + (size_t)(b * 16 + i) * 1536 + col);
    unsigned short* dst = (col < 512) ? (q_s + i * 520 + col)
                        : (col < 1024) ? (k_s + i * 520 + (col - 512))
                                       : (v_s + i * 520 + (col - 1024));
    *(uint4*)dst = d;
  }
  __syncthreads();
  if (tid < 128) {
    int h = tid >> 4, i = tid & 15;
    uint4 qv[8];
    #pragma unroll
    for (int db = 0; db < 8; ++db) qv[db] = *(const uint4*)(q_s + i * 520 + h * 64 + db * 8);
    float sc[16];
    float mx = -3e38f;
    #pragma unroll
    for (int j = 0; j < 16; ++j) {
      float acc = 0.f;
      const unsigned short* kr = k_s + j * 520 + h * 64;
      #pragma unroll
      for (int db = 0; db < 8; ++db) {
        uint4 kv = *(const uint4*)(kr + db * 8);
        acc += bflo(qv[db].x) * bflo(kv.x) + bfhi(qv[db].x) * bfhi(kv.x);
        acc += bflo(qv[db].y) * bflo(kv.y) + bfhi(qv[db].y) * bfhi(kv.y);
        acc += bflo(qv[db].z) * bflo(kv.z) + bfhi(qv[db].z) * bfhi(kv.z);
        acc += bflo(qv[db].w) * bflo(kv.w) + bfhi(qv[db].w) * bfhi(kv.w);
      }
      acc = (j <= i) ? acc * 0.125f : -3e38f;
      sc[j] = acc;
      mx = fmaxf(mx, acc);
    }
    float sum = 0.f;
    #pragma unroll
    for (int j = 0; j < 16; ++j) {
      float e = (j <= i) ? __expf(sc[j] - mx) : 0.f;
      sc[j] = e; sum += e;
    }
    float inv = 1.0f / sum;
    float* prow = p_s + (h * 16 + i) * 18;
    #pragma unroll
    for (int j = 0; j < 16; ++j) prow[j] = sc[j] * inv;
  }
  __syncthreads();
  #pragma unroll
  for (int rep = 0; rep < 4; ++rep) {
    int idx = rep * 256 + tid;      // 0..1023
    int i = idx >> 6, cb = idx & 63, col = cb * 8, h = col >> 6;
    const float* prow = p_s + (h * 16 + i) * 18;
    float o[8] = {0, 0, 0, 0, 0, 0, 0, 0};
    #pragma unroll
    for (int j = 0; j < 16; ++j) {
      float p = prow[j];
      uint4 vv = *(const uint4*)(v_s + j * 520 + col);
      o[0] += p * bflo(vv.x); o[1] += p * bfhi(vv.x);
      o[2] += p * bflo(vv.y); o[3] += p * bfhi(vv.y);
      o[4] += p * bflo(vv.z); o[5] += p * bfhi(vv.z);
      o[6] += p * bflo(vv.w); o[7] += p * bfhi(vv.w);
    }
    uint4 pk;
    pk.x = pack2(o[0], o[1]); pk.y = pack2(o[2], o[3]); pk.z = pack2(o[4], o[5]); pk.w = pack2(o[6], o[7]);
    *(uint4*)(attn_out + (size_t)(b * 16 + i) * 512 + col) = pk;
  }
}

// ---------------- K4: y = LN(attn + x) -> bf16 ----------------
__global__ __launch_bounds__(256) void ln2_kernel(
    const unsigned short* __restrict__ attn, const float* __restrict__ x,
    const float* __restrict__ lnw, const float* __restrict__ lnb, unsigned short* __restrict__ y) {
  int row = blockIdx.x * 4 + (threadIdx.x >> 6);
  int lane = threadIdx.x & 63;
  size_t base = (size_t)row * DD + lane * 8;
  uint4 av = *(const uint4*)(attn + base);
  const fx4* x4 = (const fx4*)(x + base);
  fx4 a0 = x4[0], a1 = x4[1];
  float s[8];
  s[0] = bflo(av.x) + a0[0]; s[1] = bfhi(av.x) + a0[1];
  s[2] = bflo(av.y) + a0[2]; s[3] = bfhi(av.y) + a0[3];
  s[4] = bflo(av.z) + a1[0]; s[5] = bfhi(av.z) + a1[1];
  s[6] = bflo(av.w) + a1[2]; s[7] = bfhi(av.w) + a1[3];
  float sum = 0.f;
  #pragma unroll
  for (int j = 0; j < 8; ++j) sum += s[j];
  sum = wave_sum(sum);
  float mu = sum * (1.0f / 512.0f);
  float vs = 0.f;
  #pragma unroll
  for (int j = 0; j < 8; ++j) { float d = s[j] - mu; vs += d * d; }
  vs = wave_sum(vs);
  float rs = rsqrtf(vs * (1.0f / 512.0f) + EPS_LN);
  const fx4* w4 = (const fx4*)(lnw + lane * 8);
  const fx4* bb4 = (const fx4*)(lnb + lane * 8);
  fx4 w0 = w4[0], w1 = w4[1], g0 = bb4[0], g1 = bb4[1];
  float o[8];
  #pragma unroll
  for (int j = 0; j < 4; ++j) { o[j] = (s[j] - mu) * rs * w0[j] + g0[j]; o[j+4] = (s[j+4] - mu) * rs * w1[j] + g1[j]; }
  uint4 pk;
  pk.x = pack2(o[0], o[1]); pk.y = pack2(o[2], o[3]); pk.z = pack2(o[4], o[5]); pk.w = pack2(o[6], o[7]);
  *(uint4*)(y + base) = pk;
}

// ---------------- K6: out = h @ ff2_w.T + ff2_b  (wave per row) ----------------
__global__ __launch_bounds__(256) void ff2_kernel(
    const unsigned short* __restrict__ h, const float* __restrict__ w2,
    const float* __restrict__ b2, float* __restrict__ out) {
  int row = blockIdx.x * 4 + (threadIdx.x >> 6);
  int lane = threadIdx.x & 63;
  size_t base = (size_t)row * DD + lane * 8;
  uint4 hv = *(const uint4*)(h + base);
  float f[8];
  f[0] = bflo(hv.x); f[1] = bfhi(hv.x); f[2] = bflo(hv.y); f[3] = bfhi(hv.y);
  f[4] = bflo(hv.z); f[5] = bfhi(hv.z); f[6] = bflo(hv.w); f[7] = bfhi(hv.w);
  const fx4* w0p = (const fx4*)(w2 + lane * 8);
  const fx4* w1p = (const fx4*)(w2 + 512 + lane * 8);
  fx4 w00 = w0p[0], w01 = w0p[1], w10 = w1p[0], w11 = w1p[1];
  float a0 = 0.f, a1 = 0.f;
  #pragma unroll
  for (int j = 0; j < 4; ++j) {
    a0 += f[j] * w00[j] + f[j+4] * w01[j];
    a1 += f[j] * w10[j] + f[j+4] * w11[j];
  }
  a0 = wave_sum(a0);
  a1 = wave_sum(a1);
  if (lane == 0) {
    out[(size_t)row * 2 + 0] = a0 + b2[0];
    out[(size_t)row * 2 + 1] = a1 + b2[1];
  }
}

extern "C" void kernel_launch(void* const* d_in, const int* in_sizes, int n_in,
                              void* d_out, int out_size, void* d_ws, size_t ws_size,
                              hipStream_t stream) {
  const float* x    = (const float*)d_in[0];
  const float* pcc  = (const float*)d_in[1];
  const float* pblr = (const float*)d_in[2];
  // d_in[3] exist_nodes: unused by reference
  const float* pos  = (const float*)d_in[4];
  const float* Qw   = (const float*)d_in[5];
  const float* Kw   = (const float*)d_in[6];
  const float* Vw   = (const float*)d_in[7];
  const float* lnw  = (const float*)d_in[8];
  const float* lnb  = (const float*)d_in[9];
  const float* ff1w = (const float*)d_in[10];
  const float* ff1b = (const float*)d_in[11];
  const float* pra  = (const float*)d_in[12];
  const float* ff2w = (const float*)d_in[13];
  const float* ff2b = (const float*)d_in[14];
  float* out = (float*)d_out;

  char* ws = (char*)d_ws;
  unsigned short* WqkvT = (unsigned short*)ws;                              // 1536*512*2 = 1.5 MB
  unsigned short* W1T   = (unsigned short*)(ws + 1572864);                  // 512*512*2  = 0.5 MB
  unsigned short* t_in  = (unsigned short*)(ws + 2097152);                  // 64 MB
  unsigned short* qkv   = (unsigned short*)(ws + 2097152 + 67108864);       // 192 MB
  unsigned short* attn_o = t_in;                                            // reuse (t_in dead after QKV gemm)
  unsigned short* ybuf  = qkv;                                              // reuse (qkv dead after attn)
  unsigned short* hbuf  = (unsigned short*)(ws + 2097152 + 67108864 + 67108864);

  prep_weights<<<4096, 256, 0, stream>>>(Qw, Kw, Vw, ff1w, WqkvT, W1T);
  ln1_kernel<<<NROWS / 4, 256, 0, stream>>>(x, pcc, pblr, pos, lnw, lnb, t_in);
  gemm_bt<<<dim3(NROWS / 128, 1536 / 128), 256, 0, stream>>>(t_in, WqkvT, qkv, 1536, nullptr, nullptr);
  attn_kernel<<<4096, 256, 0, stream>>>(qkv, attn_o);
  ln2_kernel<<<NROWS / 4, 256, 0, stream>>>(attn_o, x, lnw, lnb, ybuf);
  gemm_bt<<<dim3(NROWS / 128, 512 / 128), 256, 0, stream>>>(ybuf, W1T, hbuf, 512, ff1b, pra);
  ff2_kernel<<<NROWS / 4, 256, 0, stream>>>(hbuf, ff2w, ff2b, out);
}

// Round 2
// 807.973 us; speedup vs baseline: 1.0481x; 1.0481x over previous
//
#include <hip/hip_runtime.h>

#define NROWS 65536          // B*T
#define DD 512
#define EPS_LN 1e-5f

typedef __bf16 bfx8 __attribute__((ext_vector_type(8)));
typedef float fx4 __attribute__((ext_vector_type(4)));

__device__ __forceinline__ unsigned short f2bf(float f) {
  unsigned int u = __builtin_bit_cast(unsigned int, f);
  u += 0x7fffu + ((u >> 16) & 1u);          // RNE
  return (unsigned short)(u >> 16);
}
__device__ __forceinline__ float bflo(unsigned int u) { return __builtin_bit_cast(float, u << 16); }
__device__ __forceinline__ float bfhi(unsigned int u) { return __builtin_bit_cast(float, u & 0xffff0000u); }
__device__ __forceinline__ unsigned int pack2(float a, float b) {
  return (unsigned int)f2bf(a) | ((unsigned int)f2bf(b) << 16);
}
__device__ __forceinline__ float wave_sum(float v) {
  #pragma unroll
  for (int off = 32; off; off >>= 1) v += __shfl_xor(v, off);
  return v;
}
// async global(16B per lane) -> LDS(wave-uniform base + lane*16)
__device__ __forceinline__ void glds16(const unsigned short* g, unsigned short* l) {
  __builtin_amdgcn_global_load_lds(
      (const __attribute__((address_space(1))) unsigned int*)g,
      (__attribute__((address_space(3))) unsigned int*)l, 16, 0, 0);
}

// ---------------- K0: weight prep + out init ----------------
// WqkvT[j][k] (j<512:Q, <1024:K, else:V) = W[k][j] bf16.  W1T = ff1_w bf16.  out[i][j] = b2[j].
__global__ __launch_bounds__(256) void prep_weights(
    const float* __restrict__ Qw, const float* __restrict__ Kw, const float* __restrict__ Vw,
    const float* __restrict__ ff1w, const float* __restrict__ b2,
    unsigned short* __restrict__ WqkvT, unsigned short* __restrict__ W1T,
    float* __restrict__ out) {
  int idx = blockIdx.x * 256 + threadIdx.x;
  if (idx < 1536 * 512) {
    int j = idx >> 9, k = idx & 511;
    const float* src = (j < 512) ? Qw : (j < 1024 ? Kw : Vw);
    WqkvT[idx] = f2bf(src[k * 512 + (j & 511)]);
  } else if (idx < 1536 * 512 + 512 * 512) {
    int i2 = idx - 1536 * 512;
    W1T[i2] = f2bf(ff1w[i2]);
  } else {
    int i3 = idx - (1536 * 512 + 512 * 512);        // < 131072
    if (i3 < NROWS * 2) out[i3] = b2[i3 & 1];
  }
}

// ---------------- K1: x + pos + pcc + pblr -> LN -> bf16 ----------------
__global__ __launch_bounds__(256) void ln1_kernel(
    const float* __restrict__ x, const float* __restrict__ pcc, const float* __restrict__ pblr,
    const float* __restrict__ pos, const float* __restrict__ lnw, const float* __restrict__ lnb,
    unsigned short* __restrict__ t_in) {
  int row = blockIdx.x * 4 + (threadIdx.x >> 6);
  int lane = threadIdx.x & 63;
  size_t base = (size_t)row * DD + lane * 8;
  int t = row & 15;
  const fx4* x4 = (const fx4*)(x + base);
  const fx4* p4 = (const fx4*)(pcc + base);
  const fx4* q4 = (const fx4*)(pblr + base);
  const fx4* e4 = (const fx4*)(pos + t * DD + lane * 8);
  fx4 a0 = x4[0], a1 = x4[1], b0 = p4[0], b1 = p4[1], c0 = q4[0], c1 = q4[1], d0 = e4[0], d1 = e4[1];
  float s[8];
  #pragma unroll
  for (int j = 0; j < 4; ++j) { s[j] = a0[j] + b0[j] + c0[j] + d0[j]; s[j+4] = a1[j] + b1[j] + c1[j] + d1[j]; }
  float sum = 0.f;
  #pragma unroll
  for (int j = 0; j < 8; ++j) sum += s[j];
  sum = wave_sum(sum);
  float mu = sum * (1.0f / 512.0f);
  float vs = 0.f;
  #pragma unroll
  for (int j = 0; j < 8; ++j) { float d = s[j] - mu; vs += d * d; }
  vs = wave_sum(vs);
  float rs = rsqrtf(vs * (1.0f / 512.0f) + EPS_LN);
  const fx4* w4 = (const fx4*)(lnw + lane * 8);
  const fx4* bb4 = (const fx4*)(lnb + lane * 8);
  fx4 w0 = w4[0], w1 = w4[1], g0 = bb4[0], g1 = bb4[1];
  float o[8];
  #pragma unroll
  for (int j = 0; j < 4; ++j) { o[j] = (s[j] - mu) * rs * w0[j] + g0[j]; o[j+4] = (s[j+4] - mu) * rs * w1[j] + g1[j]; }
  uint4 pk;
  pk.x = pack2(o[0], o[1]); pk.y = pack2(o[2], o[3]); pk.z = pack2(o[4], o[5]); pk.w = pack2(o[6], o[7]);
  *(uint4*)(t_in + base) = pk;
}

// ---------------- GEMM  C[M][ldc] = A[M][512] * BT[N][512]^T ----------------
// m97 structure: 128x128 tile, BK=64, global_load_lds width=16, linear LDS [128][64].
// grid = (N/128, M/128): blockIdx.x walks column tiles so consecutive blocks reuse the A panel.
// FUSE: bias + PReLU + (h @ ff2^T) accumulated straight into out (no C store).
template<bool FUSE>
__global__ __launch_bounds__(256) void gemm_bt(
    const unsigned short* __restrict__ A, const unsigned short* __restrict__ BT,
    unsigned short* __restrict__ C, int ldc,
    const float* __restrict__ bias, const float* __restrict__ prelu_a,
    const float* __restrict__ w2, float* __restrict__ out) {
  __shared__ unsigned short As[128 * 64];
  __shared__ unsigned short Bs[128 * 64];
  int tid = threadIdx.x;
  int col0 = blockIdx.x * 128, row0 = blockIdx.y * 128;
  int wid = tid >> 6, lane = tid & 63;
  int wm = (wid >> 1) * 64, wn = (wid & 1) * 64;
  // staging geometry: chunk = 512 elems = 8 rows of 64; lane l -> row chunk*8 + (l>>3), col (l&7)*8
  int srow = (lane >> 3);
  int skk = (lane & 7) * 8;
  fx4 acc[4][4] = {};
  for (int k0 = 0; k0 < 512; k0 += 64) {
    #pragma unroll
    for (int c = 0; c < 4; ++c) {
      int chunk = wid * 4 + c;
      int r = chunk * 8 + srow;
      glds16(A + (size_t)(row0 + r) * 512 + k0 + skk, As + chunk * 512);
      glds16(BT + (size_t)(col0 + r) * 512 + k0 + skk, Bs + chunk * 512);
    }
    __syncthreads();
    #pragma unroll
    for (int ks = 0; ks < 2; ++ks) {
      int koff = ks * 32 + (lane >> 4) * 8;
      bfx8 af[4], bfr[4];
      #pragma unroll
      for (int m = 0; m < 4; ++m) af[m] = *(const bfx8*)(As + (wm + m * 16 + (lane & 15)) * 64 + koff);
      #pragma unroll
      for (int n = 0; n < 4; ++n) bfr[n] = *(const bfx8*)(Bs + (wn + n * 16 + (lane & 15)) * 64 + koff);
      #pragma unroll
      for (int m = 0; m < 4; ++m)
        #pragma unroll
        for (int n = 0; n < 4; ++n)
          acc[m][n] = __builtin_amdgcn_mfma_f32_16x16x32_bf16(af[m], bfr[n], acc[m][n], 0, 0, 0);
    }
    __syncthreads();
  }
  int fq = lane >> 4, fr = lane & 15;
  if constexpr (!FUSE) {
    #pragma unroll
    for (int m = 0; m < 4; ++m) {
      #pragma unroll
      for (int n = 0; n < 4; ++n) {
        int rbase = row0 + wm + m * 16 + fq * 4;
        int cidx = col0 + wn + n * 16 + fr;
        #pragma unroll
        for (int r = 0; r < 4; ++r)
          C[(size_t)(rbase + r) * ldc + cidx] = f2bf(acc[m][n][r]);
      }
    }
  } else {
    float pa = *prelu_a;
    float p0[16] = {}, p1[16] = {};     // [m*4+r] partial dots for 16 rows
    #pragma unroll
    for (int n = 0; n < 4; ++n) {
      int cidx = col0 + wn + n * 16 + fr;
      float bv = bias[cidx];
      float wa = w2[cidx], wb = w2[512 + cidx];
      #pragma unroll
      for (int m = 0; m < 4; ++m) {
        #pragma unroll
        for (int r = 0; r < 4; ++r) {
          float v = acc[m][n][r] + bv;
          v = fmaxf(v, 0.f) + pa * fminf(v, 0.f);
          p0[m * 4 + r] += v * wa;
          p1[m * 4 + r] += v * wb;
        }
      }
    }
    #pragma unroll
    for (int off = 1; off < 16; off <<= 1) {
      #pragma unroll
      for (int t = 0; t < 16; ++t) {
        p0[t] += __shfl_xor(p0[t], off);
        p1[t] += __shfl_xor(p1[t], off);
      }
    }
    if (fr == 0) {
      #pragma unroll
      for (int m = 0; m < 4; ++m) {
        #pragma unroll
        for (int r = 0; r < 4; ++r) {
          int row = row0 + wm + m * 16 + fq * 4 + r;
          __hip_atomic_fetch_add(&out[(size_t)row * 2 + 0], p0[m * 4 + r],
                                 __ATOMIC_RELAXED, __HIP_MEMORY_SCOPE_AGENT);
          __hip_atomic_fetch_add(&out[(size_t)row * 2 + 1], p1[m * 4 + r],
                                 __ATOMIC_RELAXED, __HIP_MEMORY_SCOPE_AGENT);
        }
      }
    }
  }
}

// ---------------- K3: attention per batch element, fused LN2 ----------------
__global__ __launch_bounds__(256) void attn_ln2_kernel(
    const unsigned short* __restrict__ qkv, const float* __restrict__ x,
    const float* __restrict__ lnw, const float* __restrict__ lnb,
    unsigned short* __restrict__ y) {
  __shared__ unsigned short q_s[16 * 520];
  __shared__ unsigned short k_s[16 * 520];
  __shared__ unsigned short v_s[16 * 520];
  __shared__ float p_s[8 * 16 * 18];
  int b = blockIdx.x, tid = threadIdx.x;
  #pragma unroll
  for (int c = 0; c < 12; ++c) {
    int v = c * 256 + tid;        // 0..3071 vec8 ids
    int i = v / 192, colv = v % 192, col = colv * 8;
    uint4 d = *(const uint4*)(qkv + (size_t)(b * 16 + i) * 1536 + col);
    unsigned short* dst = (col < 512) ? (q_s + i * 520 + col)
                        : (col < 1024) ? (k_s + i * 520 + (col - 512))
                                       : (v_s + i * 520 + (col - 1024));
    *(uint4*)dst = d;
  }
  __syncthreads();
  if (tid < 128) {
    int h = tid >> 4, i = tid & 15;
    uint4 qv[8];
    #pragma unroll
    for (int db = 0; db < 8; ++db) qv[db] = *(const uint4*)(q_s + i * 520 + h * 64 + db * 8);
    float sc[16];
    float mx = -3e38f;
    #pragma unroll
    for (int j = 0; j < 16; ++j) {
      float acc = 0.f;
      const unsigned short* kr = k_s + j * 520 + h * 64;
      #pragma unroll
      for (int db = 0; db < 8; ++db) {
        uint4 kv = *(const uint4*)(kr + db * 8);
        acc += bflo(qv[db].x) * bflo(kv.x) + bfhi(qv[db].x) * bfhi(kv.x);
        acc += bflo(qv[db].y) * bflo(kv.y) + bfhi(qv[db].y) * bfhi(kv.y);
        acc += bflo(qv[db].z) * bflo(kv.z) + bfhi(qv[db].z) * bfhi(kv.z);
        acc += bflo(qv[db].w) * bflo(kv.w) + bfhi(qv[db].w) * bfhi(kv.w);
      }
      acc = (j <= i) ? acc * 0.125f : -3e38f;
      sc[j] = acc;
      mx = fmaxf(mx, acc);
    }
    float sum = 0.f;
    #pragma unroll
    for (int j = 0; j < 16; ++j) {
      float e = (j <= i) ? __expf(sc[j] - mx) : 0.f;
      sc[j] = e; sum += e;
    }
    float inv = 1.0f / sum;
    float* prow = p_s + (h * 16 + i) * 18;
    #pragma unroll
    for (int j = 0; j < 16; ++j) prow[j] = sc[j] * inv;
  }
  __syncthreads();
  // PV + residual + LN2: one wave per row (lanes = 64 col-blocks of 8)
  int lane = tid & 63;
  #pragma unroll
  for (int rep = 0; rep < 4; ++rep) {
    int i = rep * 4 + (tid >> 6);
    int col = lane * 8, h = col >> 6;
    const float* prow = p_s + (h * 16 + i) * 18;
    float o[8] = {0, 0, 0, 0, 0, 0, 0, 0};
    #pragma unroll
    for (int j = 0; j < 16; ++j) {
      float p = prow[j];
      uint4 vv = *(const uint4*)(v_s + j * 520 + col);
      o[0] += p * bflo(vv.x); o[1] += p * bfhi(vv.x);
      o[2] += p * bflo(vv.y); o[3] += p * bfhi(vv.y);
      o[4] += p * bflo(vv.z); o[5] += p * bfhi(vv.z);
      o[6] += p * bflo(vv.w); o[7] += p * bfhi(vv.w);
    }
    size_t base = (size_t)(b * 16 + i) * 512 + col;
    const fx4* x4 = (const fx4*)(x + base);
    fx4 xa = x4[0], xb = x4[1];
    float s[8];
    #pragma unroll
    for (int j = 0; j < 4; ++j) { s[j] = o[j] + xa[j]; s[j+4] = o[j+4] + xb[j]; }
    float sum = 0.f;
    #pragma unroll
    for (int j = 0; j < 8; ++j) sum += s[j];
    sum = wave_sum(sum);
    float mu = sum * (1.0f / 512.0f);
    float vs = 0.f;
    #pragma unroll
    for (int j = 0; j < 8; ++j) { float d = s[j] - mu; vs += d * d; }
    vs = wave_sum(vs);
    float rs = rsqrtf(vs * (1.0f / 512.0f) + EPS_LN);
    const fx4* w4 = (const fx4*)(lnw + col);
    const fx4* bb4 = (const fx4*)(lnb + col);
    fx4 w0 = w4[0], w1 = w4[1], g0 = bb4[0], g1 = bb4[1];
    float oo[8];
    #pragma unroll
    for (int j = 0; j < 4; ++j) { oo[j] = (s[j] - mu) * rs * w0[j] + g0[j]; oo[j+4] = (s[j+4] - mu) * rs * w1[j] + g1[j]; }
    uint4 pk;
    pk.x = pack2(oo[0], oo[1]); pk.y = pack2(oo[2], oo[3]); pk.z = pack2(oo[4], oo[5]); pk.w = pack2(oo[6], oo[7]);
    *(uint4*)(y + base) = pk;
  }
}

extern "C" void kernel_launch(void* const* d_in, const int* in_sizes, int n_in,
                              void* d_out, int out_size, void* d_ws, size_t ws_size,
                              hipStream_t stream) {
  const float* x    = (const float*)d_in[0];
  const float* pcc  = (const float*)d_in[1];
  const float* pblr = (const float*)d_in[2];
  // d_in[3] exist_nodes: unused by reference
  const float* pos  = (const float*)d_in[4];
  const float* Qw   = (const float*)d_in[5];
  const float* Kw   = (const float*)d_in[6];
  const float* Vw   = (const float*)d_in[7];
  const float* lnw  = (const float*)d_in[8];
  const float* lnb  = (const float*)d_in[9];
  const float* ff1w = (const float*)d_in[10];
  const float* ff1b = (const float*)d_in[11];
  const float* pra  = (const float*)d_in[12];
  const float* ff2w = (const float*)d_in[13];
  const float* ff2b = (const float*)d_in[14];
  float* out = (float*)d_out;

  char* ws = (char*)d_ws;
  unsigned short* WqkvT = (unsigned short*)ws;                              // 1.5 MB
  unsigned short* W1T   = (unsigned short*)(ws + 1572864);                  // 0.5 MB
  unsigned short* t_in  = (unsigned short*)(ws + 2097152);                  // 64 MB
  unsigned short* qkv   = (unsigned short*)(ws + 2097152 + 67108864);       // 192 MB
  unsigned short* ybuf  = qkv;                                              // reuse (qkv dead after attn)

  prep_weights<<<4608, 256, 0, stream>>>(Qw, Kw, Vw, ff1w, ff2b, WqkvT, W1T, out);
  ln1_kernel<<<NROWS / 4, 256, 0, stream>>>(x, pcc, pblr, pos, lnw, lnb, t_in);
  gemm_bt<false><<<dim3(1536 / 128, NROWS / 128), 256, 0, stream>>>(
      t_in, WqkvT, qkv, 1536, nullptr, nullptr, nullptr, nullptr);
  attn_ln2_kernel<<<4096, 256, 0, stream>>>(qkv, x, lnw, lnb, ybuf);
  gemm_bt<true><<<dim3(512 / 128, NROWS / 128), 256, 0, stream>>>(
      ybuf, W1T, nullptr, 0, ff1b, pra, ff2w, out);
}

// Round 3
// 753.765 us; speedup vs baseline: 1.1235x; 1.0719x over previous
//
#include <hip/hip_runtime.h>

#define NROWS 65536          // B*T
#define DD 512
#define EPS_LN 1e-5f

typedef __bf16 bfx8 __attribute__((ext_vector_type(8)));
typedef float fx4 __attribute__((ext_vector_type(4)));

__device__ __forceinline__ unsigned short f2bf(float f) {
  unsigned int u = __builtin_bit_cast(unsigned int, f);
  u += 0x7fffu + ((u >> 16) & 1u);          // RNE
  return (unsigned short)(u >> 16);
}
__device__ __forceinline__ float bflo(unsigned int u) { return __builtin_bit_cast(float, u << 16); }
__device__ __forceinline__ float bfhi(unsigned int u) { return __builtin_bit_cast(float, u & 0xffff0000u); }
__device__ __forceinline__ unsigned int pack2(float a, float b) {
  return (unsigned int)f2bf(a) | ((unsigned int)f2bf(b) << 16);
}
__device__ __forceinline__ float wave_sum(float v) {
  #pragma unroll
  for (int off = 32; off; off >>= 1) v += __shfl_xor(v, off);
  return v;
}
// async global(16B per lane) -> LDS(wave-uniform base + lane*16)
__device__ __forceinline__ void glds16(const unsigned short* g, unsigned short* l) {
  __builtin_amdgcn_global_load_lds(
      (const __attribute__((address_space(1))) unsigned int*)g,
      (__attribute__((address_space(3))) unsigned int*)l, 16, 0, 0);
}

// ---------------- K0: weight prep ----------------
__global__ __launch_bounds__(256) void prep_weights(
    const float* __restrict__ Qw, const float* __restrict__ Kw, const float* __restrict__ Vw,
    const float* __restrict__ ff1w,
    unsigned short* __restrict__ WqkvT, unsigned short* __restrict__ W1T) {
  int idx = blockIdx.x * 256 + threadIdx.x;
  if (idx < 1536 * 512) {
    int j = idx >> 9, k = idx & 511;
    const float* src = (j < 512) ? Qw : (j < 1024 ? Kw : Vw);
    WqkvT[idx] = f2bf(src[k * 512 + (j & 511)]);
  } else {
    int i2 = idx - 1536 * 512;           // < 512*512 by grid sizing
    W1T[i2] = f2bf(ff1w[i2]);
  }
}

// ---------------- K1: x + pos + pcc + pblr -> LN -> bf16 ----------------
__global__ __launch_bounds__(256) void ln1_kernel(
    const float* __restrict__ x, const float* __restrict__ pcc, const float* __restrict__ pblr,
    const float* __restrict__ pos, const float* __restrict__ lnw, const float* __restrict__ lnb,
    unsigned short* __restrict__ t_in) {
  int row = blockIdx.x * 4 + (threadIdx.x >> 6);
  int lane = threadIdx.x & 63;
  size_t base = (size_t)row * DD + lane * 8;
  int t = row & 15;
  const fx4* x4 = (const fx4*)(x + base);
  const fx4* p4 = (const fx4*)(pcc + base);
  const fx4* q4 = (const fx4*)(pblr + base);
  const fx4* e4 = (const fx4*)(pos + t * DD + lane * 8);
  fx4 a0 = x4[0], a1 = x4[1], b0 = p4[0], b1 = p4[1], c0 = q4[0], c1 = q4[1], d0 = e4[0], d1 = e4[1];
  float s[8];
  #pragma unroll
  for (int j = 0; j < 4; ++j) { s[j] = a0[j] + b0[j] + c0[j] + d0[j]; s[j+4] = a1[j] + b1[j] + c1[j] + d1[j]; }
  float sum = 0.f;
  #pragma unroll
  for (int j = 0; j < 8; ++j) sum += s[j];
  sum = wave_sum(sum);
  float mu = sum * (1.0f / 512.0f);
  float vs = 0.f;
  #pragma unroll
  for (int j = 0; j < 8; ++j) { float d = s[j] - mu; vs += d * d; }
  vs = wave_sum(vs);
  float rs = rsqrtf(vs * (1.0f / 512.0f) + EPS_LN);
  const fx4* w4 = (const fx4*)(lnw + lane * 8);
  const fx4* bb4 = (const fx4*)(lnb + lane * 8);
  fx4 w0 = w4[0], w1 = w4[1], g0 = bb4[0], g1 = bb4[1];
  float o[8];
  #pragma unroll
  for (int j = 0; j < 4; ++j) { o[j] = (s[j] - mu) * rs * w0[j] + g0[j]; o[j+4] = (s[j+4] - mu) * rs * w1[j] + g1[j]; }
  uint4 pk;
  pk.x = pack2(o[0], o[1]); pk.y = pack2(o[2], o[3]); pk.z = pack2(o[4], o[5]); pk.w = pack2(o[6], o[7]);
  *(uint4*)(t_in + base) = pk;
}

// ---------------- GEMM  C[M][ldc] = A[M][512] * BT[N][512]^T ----------------
// m97 structure + T2 both-sides swizzle + T1 XCD-chunked grid.
// 1-D grid of (NT * M/128) blocks; NT = column tiles. XCD swizzle makes the NT
// sharers of one A-panel co-XCD and adjacent. LDS layout: row r, 16B-slot s
// stores logical col-chunk kb = s ^ (r&7); glds writes linearly, so the global
// SOURCE column is pre-swizzled; ds_read applies the same XOR.
template<int NT, bool EPI>
__global__ __launch_bounds__(256) void gemm_bt(
    const unsigned short* __restrict__ A, const unsigned short* __restrict__ BT,
    unsigned short* __restrict__ C, int ldc,
    const float* __restrict__ bias, const float* __restrict__ prelu_a) {
  __shared__ unsigned short As[128 * 64];
  __shared__ unsigned short Bs[128 * 64];
  int tid = threadIdx.x;
  int nwg = gridDim.x;
  int bid = blockIdx.x;
  int cpx = nwg >> 3;
  int swz = (bid & 7) * cpx + (bid >> 3);
  int col0 = (swz % NT) * 128, row0 = (swz / NT) * 128;
  int wid = tid >> 6, lane = tid & 63;
  int wm = (wid >> 1) * 64, wn = (wid & 1) * 64;
  // staging: chunk = 8 rows x 64 cols; lane l -> row chunk*8+(l>>3); pre-swizzled
  // global col-chunk kb = (l&7) ^ ((l>>3)&7)  (phys slot s=l&7, r&7=(l>>3)&7)
  int srow = (lane >> 3);
  int skk = (((lane & 7) ^ srow) & 7) * 8;
  fx4 acc[4][4] = {};
  for (int k0 = 0; k0 < 512; k0 += 64) {
    #pragma unroll
    for (int c = 0; c < 4; ++c) {
      int chunk = wid * 4 + c;
      int r = chunk * 8 + srow;
      glds16(A + (size_t)(row0 + r) * 512 + k0 + skk, As + chunk * 512);
      glds16(BT + (size_t)(col0 + r) * 512 + k0 + skk, Bs + chunk * 512);
    }
    __syncthreads();
    #pragma unroll
    for (int ks = 0; ks < 2; ++ks) {
      // logical kb = ks*4 + (lane>>4); phys slot = kb ^ (r&7), r&7 = lane&7
      int soff = ((ks * 4 + (lane >> 4)) ^ (lane & 7)) * 8;
      bfx8 af[4], bfr[4];
      #pragma unroll
      for (int m = 0; m < 4; ++m) af[m] = *(const bfx8*)(As + (wm + m * 16 + (lane & 15)) * 64 + soff);
      #pragma unroll
      for (int n = 0; n < 4; ++n) bfr[n] = *(const bfx8*)(Bs + (wn + n * 16 + (lane & 15)) * 64 + soff);
      #pragma unroll
      for (int m = 0; m < 4; ++m)
        #pragma unroll
        for (int n = 0; n < 4; ++n)
          acc[m][n] = __builtin_amdgcn_mfma_f32_16x16x32_bf16(af[m], bfr[n], acc[m][n], 0, 0, 0);
    }
    __syncthreads();
  }
  int fq = lane >> 4, fr = lane & 15;
  float pa = EPI ? *prelu_a : 0.f;
  #pragma unroll
  for (int m = 0; m < 4; ++m) {
    #pragma unroll
    for (int n = 0; n < 4; ++n) {
      int rbase = row0 + wm + m * 16 + fq * 4;
      int cidx = col0 + wn + n * 16 + fr;
      float bv = EPI ? bias[cidx] : 0.f;
      #pragma unroll
      for (int r = 0; r < 4; ++r) {
        float v = acc[m][n][r];
        if constexpr (EPI) { v += bv; v = fmaxf(v, 0.f) + pa * fminf(v, 0.f); }
        C[(size_t)(rbase + r) * ldc + cidx] = f2bf(v);
      }
    }
  }
}

// ---------------- K3: attention per batch element, fused LN2 ----------------
__global__ __launch_bounds__(256) void attn_ln2_kernel(
    const unsigned short* __restrict__ qkv, const float* __restrict__ x,
    const float* __restrict__ lnw, const float* __restrict__ lnb,
    unsigned short* __restrict__ y) {
  __shared__ unsigned short q_s[16 * 520];
  __shared__ unsigned short k_s[16 * 520];
  __shared__ unsigned short v_s[16 * 520];
  __shared__ float p_s[8 * 16 * 18];
  int b = blockIdx.x, tid = threadIdx.x;
  #pragma unroll
  for (int c = 0; c < 12; ++c) {
    int v = c * 256 + tid;        // 0..3071 vec8 ids
    int i = v / 192, colv = v % 192, col = colv * 8;
    uint4 d = *(const uint4*)(qkv + (size_t)(b * 16 + i) * 1536 + col);
    unsigned short* dst = (col < 512) ? (q_s + i * 520 + col)
                        : (col < 1024) ? (k_s + i * 520 + (col - 512))
                                       : (v_s + i * 520 + (col - 1024));
    *(uint4*)dst = d;
  }
  __syncthreads();
  if (tid < 128) {
    int h = tid >> 4, i = tid & 15;
    uint4 qv[8];
    #pragma unroll
    for (int db = 0; db < 8; ++db) qv[db] = *(const uint4*)(q_s + i * 520 + h * 64 + db * 8);
    float sc[16];
    float mx = -3e38f;
    #pragma unroll
    for (int j = 0; j < 16; ++j) {
      float acc = 0.f;
      const unsigned short* kr = k_s + j * 520 + h * 64;
      #pragma unroll
      for (int db = 0; db < 8; ++db) {
        uint4 kv = *(const uint4*)(kr + db * 8);
        acc += bflo(qv[db].x) * bflo(kv.x) + bfhi(qv[db].x) * bfhi(kv.x);
        acc += bflo(qv[db].y) * bflo(kv.y) + bfhi(qv[db].y) * bfhi(kv.y);
        acc += bflo(qv[db].z) * bflo(kv.z) + bfhi(qv[db].z) * bfhi(kv.z);
        acc += bflo(qv[db].w) * bflo(kv.w) + bfhi(qv[db].w) * bfhi(kv.w);
      }
      acc = (j <= i) ? acc * 0.125f : -3e38f;
      sc[j] = acc;
      mx = fmaxf(mx, acc);
    }
    float sum = 0.f;
    #pragma unroll
    for (int j = 0; j < 16; ++j) {
      float e = (j <= i) ? __expf(sc[j] - mx) : 0.f;
      sc[j] = e; sum += e;
    }
    float inv = 1.0f / sum;
    float* prow = p_s + (h * 16 + i) * 18;
    #pragma unroll
    for (int j = 0; j < 16; ++j) prow[j] = sc[j] * inv;
  }
  __syncthreads();
  // PV + residual + LN2: one wave per row
  int lane = tid & 63;
  #pragma unroll
  for (int rep = 0; rep < 4; ++rep) {
    int i = rep * 4 + (tid >> 6);
    int col = lane * 8, h = col >> 6;
    const float* prow = p_s + (h * 16 + i) * 18;
    float o[8] = {0, 0, 0, 0, 0, 0, 0, 0};
    #pragma unroll
    for (int j = 0; j < 16; ++j) {
      float p = prow[j];
      uint4 vv = *(const uint4*)(v_s + j * 520 + col);
      o[0] += p * bflo(vv.x); o[1] += p * bfhi(vv.x);
      o[2] += p * bflo(vv.y); o[3] += p * bfhi(vv.y);
      o[4] += p * bflo(vv.z); o[5] += p * bfhi(vv.z);
      o[6] += p * bflo(vv.w); o[7] += p * bfhi(vv.w);
    }
    size_t base = (size_t)(b * 16 + i) * 512 + col;
    const fx4* x4 = (const fx4*)(x + base);
    fx4 xa = x4[0], xb = x4[1];
    float s[8];
    #pragma unroll
    for (int j = 0; j < 4; ++j) { s[j] = o[j] + xa[j]; s[j+4] = o[j+4] + xb[j]; }
    float sum = 0.f;
    #pragma unroll
    for (int j = 0; j < 8; ++j) sum += s[j];
    sum = wave_sum(sum);
    float mu = sum * (1.0f / 512.0f);
    float vs = 0.f;
    #pragma unroll
    for (int j = 0; j < 8; ++j) { float d = s[j] - mu; vs += d * d; }
    vs = wave_sum(vs);
    float rs = rsqrtf(vs * (1.0f / 512.0f) + EPS_LN);
    const fx4* w4 = (const fx4*)(lnw + col);
    const fx4* bb4 = (const fx4*)(lnb + col);
    fx4 w0 = w4[0], w1 = w4[1], g0 = bb4[0], g1 = bb4[1];
    float oo[8];
    #pragma unroll
    for (int j = 0; j < 4; ++j) { oo[j] = (s[j] - mu) * rs * w0[j] + g0[j]; oo[j+4] = (s[j+4] - mu) * rs * w1[j] + g1[j]; }
    uint4 pk;
    pk.x = pack2(oo[0], oo[1]); pk.y = pack2(oo[2], oo[3]); pk.z = pack2(oo[4], oo[5]); pk.w = pack2(oo[6], oo[7]);
    *(uint4*)(y + base) = pk;
  }
}

// ---------------- K6: out = h @ ff2_w.T + ff2_b  (wave per row) ----------------
__global__ __launch_bounds__(256) void ff2_kernel(
    const unsigned short* __restrict__ h, const float* __restrict__ w2,
    const float* __restrict__ b2, float* __restrict__ out) {
  int row = blockIdx.x * 4 + (threadIdx.x >> 6);
  int lane = threadIdx.x & 63;
  size_t base = (size_t)row * DD + lane * 8;
  uint4 hv = *(const uint4*)(h + base);
  float f[8];
  f[0] = bflo(hv.x); f[1] = bfhi(hv.x); f[2] = bflo(hv.y); f[3] = bfhi(hv.y);
  f[4] = bflo(hv.z); f[5] = bfhi(hv.z); f[6] = bflo(hv.w); f[7] = bfhi(hv.w);
  const fx4* w0p = (const fx4*)(w2 + lane * 8);
  const fx4* w1p = (const fx4*)(w2 + 512 + lane * 8);
  fx4 w00 = w0p[0], w01 = w0p[1], w10 = w1p[0], w11 = w1p[1];
  float a0 = 0.f, a1 = 0.f;
  #pragma unroll
  for (int j = 0; j < 4; ++j) {
    a0 += f[j] * w00[j] + f[j+4] * w01[j];
    a1 += f[j] * w10[j] + f[j+4] * w11[j];
  }
  a0 = wave_sum(a0);
  a1 = wave_sum(a1);
  if (lane == 0) {
    out[(size_t)row * 2 + 0] = a0 + b2[0];
    out[(size_t)row * 2 + 1] = a1 + b2[1];
  }
}

extern "C" void kernel_launch(void* const* d_in, const int* in_sizes, int n_in,
                              void* d_out, int out_size, void* d_ws, size_t ws_size,
                              hipStream_t stream) {
  const float* x    = (const float*)d_in[0];
  const float* pcc  = (const float*)d_in[1];
  const float* pblr = (const float*)d_in[2];
  // d_in[3] exist_nodes: unused by reference
  const float* pos  = (const float*)d_in[4];
  const float* Qw   = (const float*)d_in[5];
  const float* Kw   = (const float*)d_in[6];
  const float* Vw   = (const float*)d_in[7];
  const float* lnw  = (const float*)d_in[8];
  const float* lnb  = (const float*)d_in[9];
  const float* ff1w = (const float*)d_in[10];
  const float* ff1b = (const float*)d_in[11];
  const float* pra  = (const float*)d_in[12];
  const float* ff2w = (const float*)d_in[13];
  const float* ff2b = (const float*)d_in[14];
  float* out = (float*)d_out;

  char* ws = (char*)d_ws;
  unsigned short* WqkvT = (unsigned short*)ws;                              // 1.5 MB
  unsigned short* W1T   = (unsigned short*)(ws + 1572864);                  // 0.5 MB
  unsigned short* t_in  = (unsigned short*)(ws + 2097152);                  // 64 MB
  unsigned short* qkv   = (unsigned short*)(ws + 2097152 + 67108864);       // 192 MB
  unsigned short* ybuf  = qkv;                                              // reuse (qkv dead after attn)
  unsigned short* hbuf  = t_in;                                             // reuse (t_in dead after QKV gemm)

  prep_weights<<<4096, 256, 0, stream>>>(Qw, Kw, Vw, ff1w, WqkvT, W1T);
  ln1_kernel<<<NROWS / 4, 256, 0, stream>>>(x, pcc, pblr, pos, lnw, lnb, t_in);
  gemm_bt<12, false><<<12 * (NROWS / 128), 256, 0, stream>>>(
      t_in, WqkvT, qkv, 1536, nullptr, nullptr);
  attn_ln2_kernel<<<4096, 256, 0, stream>>>(qkv, x, lnw, lnb, ybuf);
  gemm_bt<4, true><<<4 * (NROWS / 128), 256, 0, stream>>>(
      ybuf, W1T, hbuf, 512, ff1b, pra);
  ff2_kernel<<<NROWS / 4, 256, 0, stream>>>(hbuf, ff2w, ff2b, out);
}

// Round 5
// 727.986 us; speedup vs baseline: 1.1633x; 1.0354x over previous
//
#include <hip/hip_runtime.h>

#define NROWS 65536          // B*T
#define DD 512
#define EPS_LN 1e-5f

typedef __bf16 bfx8 __attribute__((ext_vector_type(8)));
typedef float fx4 __attribute__((ext_vector_type(4)));

__device__ __forceinline__ unsigned short f2bf(float f) {
  unsigned int u = __builtin_bit_cast(unsigned int, f);
  u += 0x7fffu + ((u >> 16) & 1u);          // RNE
  return (unsigned short)(u >> 16);
}
__device__ __forceinline__ float bflo(unsigned int u) { return __builtin_bit_cast(float, u << 16); }
__device__ __forceinline__ float bfhi(unsigned int u) { return __builtin_bit_cast(float, u & 0xffff0000u); }
__device__ __forceinline__ unsigned int pack2(float a, float b) {
  return (unsigned int)f2bf(a) | ((unsigned int)f2bf(b) << 16);
}
__device__ __forceinline__ float wave_sum(float v) {
  #pragma unroll
  for (int off = 32; off; off >>= 1) v += __shfl_xor(v, off);
  return v;
}
// async global(16B per lane) -> LDS(wave-uniform base + lane*16)
__device__ __forceinline__ void glds16(const unsigned short* g, unsigned short* l) {
  __builtin_amdgcn_global_load_lds(
      (const __attribute__((address_space(1))) unsigned int*)g,
      (__attribute__((address_space(3))) unsigned int*)l, 16, 0, 0);
}

// ---------------- K0: weight prep ----------------
__global__ __launch_bounds__(256) void prep_weights(
    const float* __restrict__ Qw, const float* __restrict__ Kw, const float* __restrict__ Vw,
    const float* __restrict__ ff1w,
    unsigned short* __restrict__ WqkvT, unsigned short* __restrict__ W1T) {
  int idx = blockIdx.x * 256 + threadIdx.x;
  if (idx < 1536 * 512) {
    int j = idx >> 9, k = idx & 511;
    const float* src = (j < 512) ? Qw : (j < 1024 ? Kw : Vw);
    WqkvT[idx] = f2bf(src[k * 512 + (j & 511)]);
  } else {
    int i2 = idx - 1536 * 512;           // < 512*512 by grid sizing
    W1T[i2] = f2bf(ff1w[i2]);
  }
}

// ---------------- K1: x + pos + pcc + pblr -> LN -> bf16 ----------------
__global__ __launch_bounds__(256) void ln1_kernel(
    const float* __restrict__ x, const float* __restrict__ pcc, const float* __restrict__ pblr,
    const float* __restrict__ pos, const float* __restrict__ lnw, const float* __restrict__ lnb,
    unsigned short* __restrict__ t_in) {
  int row = blockIdx.x * 4 + (threadIdx.x >> 6);
  int lane = threadIdx.x & 63;
  size_t base = (size_t)row * DD + lane * 8;
  int t = row & 15;
  const fx4* x4 = (const fx4*)(x + base);
  const fx4* p4 = (const fx4*)(pcc + base);
  const fx4* q4 = (const fx4*)(pblr + base);
  const fx4* e4 = (const fx4*)(pos + t * DD + lane * 8);
  fx4 a0 = x4[0], a1 = x4[1], b0 = p4[0], b1 = p4[1], c0 = q4[0], c1 = q4[1], d0 = e4[0], d1 = e4[1];
  float s[8];
  #pragma unroll
  for (int j = 0; j < 4; ++j) { s[j] = a0[j] + b0[j] + c0[j] + d0[j]; s[j+4] = a1[j] + b1[j] + c1[j] + d1[j]; }
  float sum = 0.f;
  #pragma unroll
  for (int j = 0; j < 8; ++j) sum += s[j];
  sum = wave_sum(sum);
  float mu = sum * (1.0f / 512.0f);
  float vs = 0.f;
  #pragma unroll
  for (int j = 0; j < 8; ++j) { float d = s[j] - mu; vs += d * d; }
  vs = wave_sum(vs);
  float rs = rsqrtf(vs * (1.0f / 512.0f) + EPS_LN);
  const fx4* w4 = (const fx4*)(lnw + lane * 8);
  const fx4* bb4 = (const fx4*)(lnb + lane * 8);
  fx4 w0 = w4[0], w1 = w4[1], g0 = bb4[0], g1 = bb4[1];
  float o[8];
  #pragma unroll
  for (int j = 0; j < 4; ++j) { o[j] = (s[j] - mu) * rs * w0[j] + g0[j]; o[j+4] = (s[j+4] - mu) * rs * w1[j] + g1[j]; }
  uint4 pk;
  pk.x = pack2(o[0], o[1]); pk.y = pack2(o[2], o[3]); pk.z = pack2(o[4], o[5]); pk.w = pack2(o[6], o[7]);
  *(uint4*)(t_in + base) = pk;
}

// ---------------- GEMM  C[M][ldc] = A[M][512] * BT[N][512]^T ----------------
// m97 structure + T2 both-sides swizzle + T1 XCD-chunked grid. (unchanged from R3)
template<int NT, bool EPI>
__global__ __launch_bounds__(256) void gemm_bt(
    const unsigned short* __restrict__ A, const unsigned short* __restrict__ BT,
    unsigned short* __restrict__ C, int ldc,
    const float* __restrict__ bias, const float* __restrict__ prelu_a) {
  __shared__ unsigned short As[128 * 64];
  __shared__ unsigned short Bs[128 * 64];
  int tid = threadIdx.x;
  int nwg = gridDim.x;
  int bid = blockIdx.x;
  int cpx = nwg >> 3;
  int swz = (bid & 7) * cpx + (bid >> 3);
  int col0 = (swz % NT) * 128, row0 = (swz / NT) * 128;
  int wid = tid >> 6, lane = tid & 63;
  int wm = (wid >> 1) * 64, wn = (wid & 1) * 64;
  int srow = (lane >> 3);
  int skk = (((lane & 7) ^ srow) & 7) * 8;
  fx4 acc[4][4] = {};
  for (int k0 = 0; k0 < 512; k0 += 64) {
    #pragma unroll
    for (int c = 0; c < 4; ++c) {
      int chunk = wid * 4 + c;
      int r = chunk * 8 + srow;
      glds16(A + (size_t)(row0 + r) * 512 + k0 + skk, As + chunk * 512);
      glds16(BT + (size_t)(col0 + r) * 512 + k0 + skk, Bs + chunk * 512);
    }
    __syncthreads();
    #pragma unroll
    for (int ks = 0; ks < 2; ++ks) {
      int soff = ((ks * 4 + (lane >> 4)) ^ (lane & 7)) * 8;
      bfx8 af[4], bfr[4];
      #pragma unroll
      for (int m = 0; m < 4; ++m) af[m] = *(const bfx8*)(As + (wm + m * 16 + (lane & 15)) * 64 + soff);
      #pragma unroll
      for (int n = 0; n < 4; ++n) bfr[n] = *(const bfx8*)(Bs + (wn + n * 16 + (lane & 15)) * 64 + soff);
      #pragma unroll
      for (int m = 0; m < 4; ++m)
        #pragma unroll
        for (int n = 0; n < 4; ++n)
          acc[m][n] = __builtin_amdgcn_mfma_f32_16x16x32_bf16(af[m], bfr[n], acc[m][n], 0, 0, 0);
    }
    __syncthreads();
  }
  int fq = lane >> 4, fr = lane & 15;
  float pa = EPI ? *prelu_a : 0.f;
  #pragma unroll
  for (int m = 0; m < 4; ++m) {
    #pragma unroll
    for (int n = 0; n < 4; ++n) {
      int rbase = row0 + wm + m * 16 + fq * 4;
      int cidx = col0 + wn + n * 16 + fr;
      float bv = EPI ? bias[cidx] : 0.f;
      #pragma unroll
      for (int r = 0; r < 4; ++r) {
        float v = acc[m][n][r];
        if constexpr (EPI) { v += bv; v = fmaxf(v, 0.f) + pa * fminf(v, 0.f); }
        C[(size_t)(rbase + r) * ldc + cidx] = f2bf(v);
      }
    }
  }
}

// ---------------- K3: attention per batch element (MFMA QK^T), fused LN2 ----------------
// 256 threads = 4 waves; wave w owns heads 2w, 2w+1.
// QK^T: A-frag = Q rows (direct from global), B-frag = K rows from XOR-swizzled LDS.
// S layout (m89): col j = lane&15, row i = (lane>>4)*4 + r. Softmax = shfl_xor over j-lanes.
// P -> p_s (f32, bank-skewed). PV + residual + LN2 on all 256 threads.
__global__ __launch_bounds__(256) void attn_ln2_kernel(
    const unsigned short* __restrict__ qkv, const float* __restrict__ x,
    const float* __restrict__ lnw, const float* __restrict__ lnb,
    unsigned short* __restrict__ y) {
  __shared__ __attribute__((aligned(16))) unsigned short k_s[16 * 576]; // row stride 1152B, chunk^(row&7) swizzle
  __shared__ __attribute__((aligned(16))) unsigned short v_s[16 * 520];
  __shared__ float p_s[8 * 16 * 18 + 16];   // row(h,i) base = (h*16+i)*18 + h*2 (bank skew)
  int b = blockIdx.x, tid = threadIdx.x;
  // stage K,V: 16 rows x 1024 cols (qkv cols 512..1535) = 2048 uint4, 8/thread
  #pragma unroll
  for (int c = 0; c < 8; ++c) {
    int v = c * 256 + tid;
    int i = v >> 7, colv = v & 127;
    uint4 d = *(const uint4*)(qkv + (size_t)(b * 16 + i) * 1536 + 512 + colv * 8);
    if (colv < 64) {
      int ph = colv ^ (i & 7);
      *(uint4*)(k_s + i * 576 + ph * 8) = d;
    } else {
      *(uint4*)(v_s + i * 520 + (colv - 64) * 8) = d;
    }
  }
  __syncthreads();
  // ---- QK^T + softmax (all 4 waves, 2 heads each) ----
  {
    int wv = tid >> 6, lane = tid & 63;
    int g = lane >> 4, fr = lane & 15;
    #pragma unroll
    for (int hh = 0; hh < 2; ++hh) {
      int h = wv * 2 + hh;
      fx4 s = {};
      #pragma unroll
      for (int ks = 0; ks < 2; ++ks) {
        bfx8 aq = *(const bfx8*)(qkv + (size_t)(b * 16 + fr) * 1536 + h * 64 + ks * 32 + g * 8);
        int ch = (h * 8 + ks * 4 + g) ^ (fr & 7);
        bfx8 bk = *(const bfx8*)(k_s + fr * 576 + ch * 8);
        s = __builtin_amdgcn_mfma_f32_16x16x32_bf16(aq, bk, s, 0, 0, 0);
      }
      #pragma unroll
      for (int r = 0; r < 4; ++r) {
        int i = g * 4 + r;
        bool keep = (fr <= i);
        float sv = keep ? s[r] * 0.125f : -1e30f;
        float m = sv;
        #pragma unroll
        for (int off = 1; off < 16; off <<= 1) m = fmaxf(m, __shfl_xor(m, off));
        float e = keep ? __expf(sv - m) : 0.f;
        float sum = e;
        #pragma unroll
        for (int off = 1; off < 16; off <<= 1) sum += __shfl_xor(sum, off);
        p_s[(h * 16 + i) * 18 + h * 2 + fr] = e / sum;
      }
    }
  }
  __syncthreads();
  // ---- PV + residual + LN2: one wave per row ----
  int lane = tid & 63;
  #pragma unroll
  for (int rep = 0; rep < 4; ++rep) {
    int i = rep * 4 + (tid >> 6);
    int col = lane * 8, h = lane >> 3;
    const float* prow = p_s + (h * 16 + i) * 18 + h * 2;
    float o[8] = {0, 0, 0, 0, 0, 0, 0, 0};
    #pragma unroll
    for (int j = 0; j < 16; ++j) {
      float p = prow[j];
      uint4 vv = *(const uint4*)(v_s + j * 520 + col);
      o[0] += p * bflo(vv.x); o[1] += p * bfhi(vv.x);
      o[2] += p * bflo(vv.y); o[3] += p * bfhi(vv.y);
      o[4] += p * bflo(vv.z); o[5] += p * bfhi(vv.z);
      o[6] += p * bflo(vv.w); o[7] += p * bfhi(vv.w);
    }
    size_t base = (size_t)(b * 16 + i) * 512 + col;
    const fx4* x4 = (const fx4*)(x + base);
    fx4 xa = x4[0], xb = x4[1];
    float s[8];
    #pragma unroll
    for (int j = 0; j < 4; ++j) { s[j] = o[j] + xa[j]; s[j+4] = o[j+4] + xb[j]; }
    float sum = 0.f;
    #pragma unroll
    for (int j = 0; j < 8; ++j) sum += s[j];
    sum = wave_sum(sum);
    float mu = sum * (1.0f / 512.0f);
    float vs = 0.f;
    #pragma unroll
    for (int j = 0; j < 8; ++j) { float d = s[j] - mu; vs += d * d; }
    vs = wave_sum(vs);
    float rs = rsqrtf(vs * (1.0f / 512.0f) + EPS_LN);
    const fx4* w4 = (const fx4*)(lnw + col);
    const fx4* bb4 = (const fx4*)(lnb + col);
    fx4 w0 = w4[0], w1 = w4[1], g0 = bb4[0], g1 = bb4[1];
    float oo[8];
    #pragma unroll
    for (int j = 0; j < 4; ++j) { oo[j] = (s[j] - mu) * rs * w0[j] + g0[j]; oo[j+4] = (s[j+4] - mu) * rs * w1[j] + g1[j]; }
    uint4 pk;
    pk.x = pack2(oo[0], oo[1]); pk.y = pack2(oo[2], oo[3]); pk.z = pack2(oo[4], oo[5]); pk.w = pack2(oo[6], oo[7]);
    *(uint4*)(y + base) = pk;
  }
}

// ---------------- K6: out = h @ ff2_w.T + ff2_b  (wave per row) ----------------
__global__ __launch_bounds__(256) void ff2_kernel(
    const unsigned short* __restrict__ h, const float* __restrict__ w2,
    const float* __restrict__ b2, float* __restrict__ out) {
  int row = blockIdx.x * 4 + (threadIdx.x >> 6);
  int lane = threadIdx.x & 63;
  size_t base = (size_t)row * DD + lane * 8;
  uint4 hv = *(const uint4*)(h + base);
  float f[8];
  f[0] = bflo(hv.x); f[1] = bfhi(hv.x); f[2] = bflo(hv.y); f[3] = bfhi(hv.y);
  f[4] = bflo(hv.z); f[5] = bfhi(hv.z); f[6] = bflo(hv.w); f[7] = bfhi(hv.w);
  const fx4* w0p = (const fx4*)(w2 + lane * 8);
  const fx4* w1p = (const fx4*)(w2 + 512 + lane * 8);
  fx4 w00 = w0p[0], w01 = w0p[1], w10 = w1p[0], w11 = w1p[1];
  float a0 = 0.f, a1 = 0.f;
  #pragma unroll
  for (int j = 0; j < 4; ++j) {
    a0 += f[j] * w00[j] + f[j+4] * w01[j];
    a1 += f[j] * w10[j] + f[j+4] * w11[j];
  }
  a0 = wave_sum(a0);
  a1 = wave_sum(a1);
  if (lane == 0) {
    out[(size_t)row * 2 + 0] = a0 + b2[0];
    out[(size_t)row * 2 + 1] = a1 + b2[1];
  }
}

extern "C" void kernel_launch(void* const* d_in, const int* in_sizes, int n_in,
                              void* d_out, int out_size, void* d_ws, size_t ws_size,
                              hipStream_t stream) {
  const float* x    = (const float*)d_in[0];
  const float* pcc  = (const float*)d_in[1];
  const float* pblr = (const float*)d_in[2];
  // d_in[3] exist_nodes: unused by reference
  const float* pos  = (const float*)d_in[4];
  const float* Qw   = (const float*)d_in[5];
  const float* Kw   = (const float*)d_in[6];
  const float* Vw   = (const float*)d_in[7];
  const float* lnw  = (const float*)d_in[8];
  const float* lnb  = (const float*)d_in[9];
  const float* ff1w = (const float*)d_in[10];
  const float* ff1b = (const float*)d_in[11];
  const float* pra  = (const float*)d_in[12];
  const float* ff2w = (const float*)d_in[13];
  const float* ff2b = (const float*)d_in[14];
  float* out = (float*)d_out;

  char* ws = (char*)d_ws;
  unsigned short* WqkvT = (unsigned short*)ws;                              // 1.5 MB
  unsigned short* W1T   = (unsigned short*)(ws + 1572864);                  // 0.5 MB
  unsigned short* t_in  = (unsigned short*)(ws + 2097152);                  // 64 MB
  unsigned short* qkv   = (unsigned short*)(ws + 2097152 + 67108864);       // 192 MB
  unsigned short* ybuf  = qkv;                                              // reuse (qkv dead after attn)
  unsigned short* hbuf  = t_in;                                             // reuse (t_in dead after QKV gemm)

  prep_weights<<<4096, 256, 0, stream>>>(Qw, Kw, Vw, ff1w, WqkvT, W1T);
  ln1_kernel<<<NROWS / 4, 256, 0, stream>>>(x, pcc, pblr, pos, lnw, lnb, t_in);
  gemm_bt<12, false><<<12 * (NROWS / 128), 256, 0, stream>>>(
      t_in, WqkvT, qkv, 1536, nullptr, nullptr);
  attn_ln2_kernel<<<4096, 256, 0, stream>>>(qkv, x, lnw, lnb, ybuf);
  gemm_bt<4, true><<<4 * (NROWS / 128), 256, 0, stream>>>(
      ybuf, W1T, hbuf, 512, ff1b, pra);
  ff2_kernel<<<NROWS / 4, 256, 0, stream>>>(hbuf, ff2w, ff2b, out);
}